// Round 10
// baseline (452.017 us; speedup 1.0000x reference)
//
#include <hip/hip_runtime.h>

typedef short s8v __attribute__((ext_vector_type(8)));   // 8 bf16 (guide §3 frag_ab)
typedef float f4v __attribute__((ext_vector_type(4)));   // MFMA accumulator
typedef int   i4v __attribute__((ext_vector_type(4)));   // 16B int view for reg pin

#define LOG2E 1.4426950408889634f
#define LN2   0.6931471805599453f

// Raw barrier: LDS visibility only (lgkmcnt), vmcnt floats -> global prefetch stays async.
#define SYNC_LDS() __asm__ __volatile__("s_waitcnt lgkmcnt(0)\n\ts_barrier" ::: "memory")

__device__ __forceinline__ float fast_exp2(float x) {
#if __has_builtin(__builtin_amdgcn_exp2f)
    return __builtin_amdgcn_exp2f(x);
#else
    return exp2f(x);
#endif
}

// f32 -> bf16 (RNE). bf16 keeps the full f32 exponent range: no under/overflow.
__device__ __forceinline__ unsigned short f2bf(float x) {
    unsigned int u = __float_as_uint(x);
    return (unsigned short)((u + 0x7fffu + ((u >> 16) & 1u)) >> 16);
}

// ONE chain per block, TWO waves per block (128 threads). Wave w owns output
// columns 128w..128w+127 (8 MFMA col-tiles); E half resides in the wave's VGPRs
// (128 regs). Thread owns exactly 2 states: j0 = 128w + lane, j1 = j0 + 64
// (tile lg and tile lg+4, slot ll) -> coalesced emission loads, own-state writes.
// Exp-space linear recursion; matvec on MFMA (A = u chunks, rows replicated);
// one raw barrier per step; renorm by exponent of previous u(0) (exact pow2).
__launch_bounds__(128, 1)
__global__ void crf_main(const float* __restrict__ emissions,
                         const int*   __restrict__ tags,
                         const float* __restrict__ mask,
                         const float* __restrict__ trans,
                         float*       __restrict__ ws) {
    const int T = 512, N = 256;
    const int b   = blockIdx.x;
    const int tid = threadIdx.x;      // 0..127
    const int l   = tid & 63;
    const int w   = tid >> 6;         // wave 0/1
    const int lg  = l >> 4;           // 16-lane group
    const int ll  = l & 15;           // slot in group
    const int j0  = 128 * w + l;      // owned state 0 (col of tile lg)
    const int j1  = j0 + 64;          // owned state 1 (col of tile lg+4)

    __shared__ alignas(16) unsigned short u_lds[2][256];  // u as bf16, double-buffered
    __shared__ float cm2_lds[256];
    __shared__ float red[128];

    // ---- per-column log2-max of trans for own 2 columns ----
    {
        const float* t0 = trans + j0;
        const float* t1 = trans + j1;
        float m0 = -1e30f, m1 = -1e30f;
        #pragma unroll 8
        for (int i = 0; i < N; ++i) { m0 = fmaxf(m0, t0[i*N]); m1 = fmaxf(m1, t1[i*N]); }
        cm2_lds[j0] = m0 * LOG2E;
        cm2_lds[j1] = m1 * LOG2E;
    }
    __syncthreads();
    const float cm0 = cm2_lds[j0];
    const float cm1 = cm2_lds[j1];

    // ---- E fragments: 8 tiles (cols 128w+16c+ll) x 8 chunks (k = 32q+8lg+e) ----
    // Same slot-map for A and B packing -> any HW k-permutation cancels.
    s8v Efr[8][8];
    #pragma unroll
    for (int c = 0; c < 8; ++c) {
        const int   col = 128 * w + 16 * c + ll;
        const float cc  = cm2_lds[col];
        #pragma unroll
        for (int q = 0; q < 8; ++q) {
            s8v e;
            #pragma unroll
            for (int el = 0; el < 8; ++el) {
                const int k = 32 * q + 8 * lg + el;
                e[el] = (short)f2bf(fast_exp2(trans[k * N + col] * LOG2E - cc));
            }
            i4v ei = __builtin_bit_cast(i4v, e);
            asm volatile("" : "+v"(ei));       // keep in arch VGPRs
            Efr[c][q] = __builtin_bit_cast(s8v, ei);
        }
    }

    // ---- init: u_0 = bf16(2^(log2e*emit0)) for own 2 states; prefetch em t=1,2 ----
    const float* embase = emissions + ((size_t)b * T) * N;
    u_lds[0][j0] = f2bf(fast_exp2(embase[j0] * LOG2E));
    u_lds[0][j1] = f2bf(fast_exp2(embase[j1] * LOG2E));
    float C = 0.f;
    float emA0 = embase[(size_t)1 * N + j0], emA1 = embase[(size_t)1 * N + j1];
    float emB0 = embase[(size_t)2 * N + j0], emB1 = embase[(size_t)2 * N + j1];
    SYNC_LDS();

    float v0f = 0.f, v1f = 0.f;   // final-step unpacked u values (own states)

#define STEP(tt, eP0, eP1)  do {                                                   \
    const int pb = ((tt) - 1) & 1, cb = (tt) & 1;                                  \
    const uint4* ub = (const uint4*)u_lds[pb];                                     \
    s8v ua[8];                                                                     \
    _Pragma("unroll")                                                              \
    for (int q = 0; q < 8; ++q) ua[q] = __builtin_bit_cast(s8v, ub[4*q + lg]);     \
    const unsigned int u0b = u_lds[pb][0];                                         \
    const float use0 = eP0, use1 = eP1;                                            \
    if ((tt) + 2 < T) {                                                            \
        eP0 = embase[(size_t)((tt) + 2) * N + j0];                                 \
        eP1 = embase[(size_t)((tt) + 2) * N + j1];                                 \
    }                                                                              \
    const int   ee = (int)((u0b >> 7) & 0xffu);                                    \
    const float rr = __int_as_float((250 - ee) << 23);                             \
    C += (float)(ee - 123);                                                        \
    const float ss0 = fast_exp2(fmaf(use0, LOG2E, cm0)) * rr;                      \
    const float ss1 = fast_exp2(fmaf(use1, LOG2E, cm1)) * rr;                      \
    f4v z = {0.f, 0.f, 0.f, 0.f};                                                  \
    f4v d0 = z, d1 = z, d2 = z, d3 = z, d4 = z, d5 = z, d6 = z, d7 = z;            \
    _Pragma("unroll")                                                              \
    for (int q = 0; q < 8; ++q) {                                                  \
        d0 = __builtin_amdgcn_mfma_f32_16x16x32_bf16(ua[q], Efr[0][q], d0, 0,0,0); \
        d1 = __builtin_amdgcn_mfma_f32_16x16x32_bf16(ua[q], Efr[1][q], d1, 0,0,0); \
        d2 = __builtin_amdgcn_mfma_f32_16x16x32_bf16(ua[q], Efr[2][q], d2, 0,0,0); \
        d3 = __builtin_amdgcn_mfma_f32_16x16x32_bf16(ua[q], Efr[3][q], d3, 0,0,0); \
        d4 = __builtin_amdgcn_mfma_f32_16x16x32_bf16(ua[q], Efr[4][q], d4, 0,0,0); \
        d5 = __builtin_amdgcn_mfma_f32_16x16x32_bf16(ua[q], Efr[5][q], d5, 0,0,0); \
        d6 = __builtin_amdgcn_mfma_f32_16x16x32_bf16(ua[q], Efr[6][q], d6, 0,0,0); \
        d7 = __builtin_amdgcn_mfma_f32_16x16x32_bf16(ua[q], Efr[7][q], d7, 0,0,0); \
    }                                                                              \
    const float a0 = (lg==0) ? d0[0] : (lg==1) ? d1[0] : (lg==2) ? d2[0] : d3[0];  \
    const float a1 = (lg==0) ? d4[0] : (lg==1) ? d5[0] : (lg==2) ? d6[0] : d7[0];  \
    v0f = a0 * ss0;                                                                \
    v1f = a1 * ss1;                                                                \
    u_lds[cb][j0] = f2bf(v0f);                                                     \
    u_lds[cb][j1] = f2bf(v1f);                                                     \
    SYNC_LDS();                                                                    \
} while (0)

    for (int t = 1; t + 1 < T; t += 2) {
        STEP(t,     emA0, emA1);
        STEP(t + 1, emB0, emB1);
    }
    STEP(T - 1, emA0, emA1);     // T-1 = 511 is odd -> A-parity
#undef STEP

    // ---- Z_b = ln2 * (C + log2(sum_j u_j)) ; u summed from pre-pack f32 ----
    float s = v0f + v1f;         // own 2 states, no redundancy
    #pragma unroll
    for (int d = 32; d > 0; d >>= 1) s += __shfl_down(s, d);
    if (l == 0) red[w] = s;
    __syncthreads();
    float Z = 0.f;
    if (tid == 0) Z = (C + log2f(red[0] + red[1])) * LN2;
    __syncthreads();             // red reuse below

    // ---- gold score (gather), 128 threads ----
    float gp = 0.f;
    const int*   tg = tags + (size_t)b * T;
    const float* mk = mask + (size_t)b * T;
    for (int t = 1 + tid; t < T; t += 128) {
        int tt = tg[t], tp = tg[t - 1];
        gp += (embase[(size_t)t * N + tt] + trans[(size_t)tp * N + tt]) * mk[t];
    }
    if (tid == 0) gp += embase[tg[0]];
    red[tid] = gp;
    __syncthreads();
    #pragma unroll
    for (int s2 = 64; s2 > 0; s2 >>= 1) {
        if (tid < s2) red[tid] += red[tid + s2];
        __syncthreads();
    }
    if (tid == 0) ws[b] = Z - red[0];
}

// Deterministic mean over the 128 per-batch results.
__global__ void crf_finalize(const float* __restrict__ ws, float* __restrict__ out) {
    int l = threadIdx.x;                 // 64 threads, one wave
    float s = ws[l] + ws[l + 64];
    #pragma unroll
    for (int d = 32; d > 0; d >>= 1) s += __shfl_down(s, d);
    if (l == 0) out[0] = s * (1.0f / 128.0f);
}

extern "C" void kernel_launch(void* const* d_in, const int* in_sizes, int n_in,
                              void* d_out, int out_size, void* d_ws, size_t ws_size,
                              hipStream_t stream) {
    const float* emissions = (const float*)d_in[0];
    const int*   tags      = (const int*)  d_in[1];
    const float* mask      = (const float*)d_in[2];
    const float* trans     = (const float*)d_in[3];
    float* out = (float*)d_out;
    float* ws  = (float*)d_ws;           // 128 floats of scratch

    crf_main<<<dim3(128), dim3(128), 0, stream>>>(emissions, tags, mask, trans, ws);
    crf_finalize<<<dim3(1), dim3(64), 0, stream>>>(ws, out);
}

// Round 11
// 231.749 us; speedup vs baseline: 1.9505x; 1.9505x over previous
//
#include <hip/hip_runtime.h>

typedef float f4v __attribute__((ext_vector_type(4)));   // MFMA accumulator
typedef int   i8v __attribute__((ext_vector_type(8)));   // 32 fp8 bytes (8 VGPRs)

#define LOG2E 1.4426950408889634f
#define LN2   0.6931471805599453f
#define SC1   0x7F7F7F7F   // four e8m0 scale factors of 1.0

// Raw barrier: LDS visibility only (lgkmcnt); vmcnt floats -> global prefetch stays async.
#define SYNC_LDS() __asm__ __volatile__("s_waitcnt lgkmcnt(0)\n\ts_barrier" ::: "memory")

__device__ __forceinline__ float fast_exp2(float x) {
#if __has_builtin(__builtin_amdgcn_exp2f)
    return __builtin_amdgcn_exp2f(x);
#else
    return exp2f(x);
#endif
}

// f32 -> bf8 (e5m2) low byte. e5m2 range ~2^-16..2^15.5 absorbs stale-renorm drift.
__device__ __forceinline__ unsigned char f2bf8(float x) {
    return (unsigned char)(__builtin_amdgcn_cvt_pk_bf8_f32(x, x, 0, false) & 0xff);
}

// One block per batch element b; thread j owns output column j (= 64*wave + lane).
// Exp-space linear recursion; matvec on the K=128 block-scaled MX MFMA (scales = 1.0):
//   A (16x128) = u chunk as bf8, all 16 rows identical -> all D rows equal v.
//   B (128x16) = E slice as fp8 e4m3, VGPR-resident for the whole kernel.
// Per wave per step: 4 ds_read_b128 + 8 MFMAs (4 tiles x 2 K-chunks, depth-2 chains).
// One raw barrier per step; u renormalized by exponent of previous stored u(0)
// (memoryless, exact pow2, C-accounted) -- the R7/R8-proven scheme.
__launch_bounds__(256, 1)
__global__ void crf_main(const float* __restrict__ emissions,
                         const int*   __restrict__ tags,
                         const float* __restrict__ mask,
                         const float* __restrict__ trans,
                         float*       __restrict__ ws) {
    const int T = 512, N = 256;
    const int b  = blockIdx.x;
    const int j  = threadIdx.x;
    const int l  = j & 63;          // lane
    const int w  = j >> 6;          // wave
    const int lg = l >> 4;          // 16-lane group (K sub-chunk)
    const int ll = l & 15;          // position in group (N dim)

    __shared__ alignas(16) unsigned char u_lds[2][256];  // u as bf8, double-buffered
    __shared__ float cm2_lds[256];
    __shared__ float red[256];

    // ---- per-column log2-max of trans (thread j -> column j, coalesced) ----
    const float* tcol = trans + j;
    float cmax = -1e30f;
    #pragma unroll 8
    for (int i = 0; i < N; ++i) cmax = fmaxf(cmax, tcol[i * N]);
    cm2_lds[j] = cmax * LOG2E;
    __syncthreads();
    const float cm2 = cm2_lds[j];   // own column's, kept in a register

    // ---- E fragments (B operand) as fp8 e4m3, registers for the whole kernel ----
    // tile c: cols 64w+16c+ll ; chunk q: byte-slot e holds k = 128q + 32lg + e.
    // A is packed with the SAME k-map -> any HW k-permutation cancels; scales are
    // all 1.0 so the 32-elem scale-block mapping is irrelevant.
    i8v Efr[4][2];
    #pragma unroll
    for (int c = 0; c < 4; ++c) {
        const int   col = 64 * w + 16 * c + ll;
        const float cc  = cm2_lds[col];
        #pragma unroll
        for (int q = 0; q < 2; ++q) {
            i8v ev;
            #pragma unroll
            for (int d = 0; d < 8; ++d) {
                const int k0 = 128 * q + 32 * lg + 4 * d;
                float f0 = fast_exp2(trans[(k0 + 0) * N + col] * LOG2E - cc);
                float f1 = fast_exp2(trans[(k0 + 1) * N + col] * LOG2E - cc);
                float f2 = fast_exp2(trans[(k0 + 2) * N + col] * LOG2E - cc);
                float f3 = fast_exp2(trans[(k0 + 3) * N + col] * LOG2E - cc);
                int pk = __builtin_amdgcn_cvt_pk_fp8_f32(f0, f1, 0, false);
                pk     = __builtin_amdgcn_cvt_pk_fp8_f32(f2, f3, pk, true);
                ev[d] = pk;
            }
            Efr[c][q] = ev;
        }
    }

    // ---- init: u_0 = bf8(2^(log2e * emit[b,0,j])), C = 0 ----
    const float* em_base = emissions + ((size_t)b * T) * N + j;
    float v = fast_exp2(em_base[0] * LOG2E);   // |log2 v| <= ~6: well inside e5m2
    float C = 0.f;
    float em_next  = em_base[N];
    float em_next2 = em_base[2 * N];
    u_lds[0][j] = f2bf8(v);
    SYNC_LDS();

    for (int t = 1; t < T; ++t) {
        const int pb = (t - 1) & 1;
        // u fragments: chunk q -> 32 bytes at offset 128q + 32lg (two b128 reads,
        // 16-lane broadcast per group, groups hit distinct banks: conflict-free)
        const uint4* ub4 = (const uint4*)u_lds[pb];
        uint4 a0 = ub4[2 * lg],     a1 = ub4[2 * lg + 1];      // q = 0
        uint4 b0 = ub4[8 + 2 * lg], b1 = ub4[8 + 2 * lg + 1];  // q = 1
        i8v ua0, ua1;
        ua0[0]=a0.x; ua0[1]=a0.y; ua0[2]=a0.z; ua0[3]=a0.w;
        ua0[4]=a1.x; ua0[5]=a1.y; ua0[6]=a1.z; ua0[7]=a1.w;
        ua1[0]=b0.x; ua1[1]=b0.y; ua1[2]=b0.z; ua1[3]=b0.w;
        ua1[4]=b1.x; ua1[5]=b1.y; ua1[6]=b1.z; ua1[7]=b1.w;
        const unsigned int u0b = u_lds[pb][0];   // exponent reference (bf8 byte)

        float em = em_next;
        em_next = em_next2;
        if (t + 2 < T) em_next2 = em_base[(size_t)(t + 2) * N];  // vmcnt never drained

        // ---- hoisted scale: k from prev u(0)'s e5m2 exponent; r = 2^-(k+6) exact ----
        const int   eb   = (int)((u0b >> 2) & 0x1fu);
        const int   k    = (eb ? eb : 1) - 15;
        const float r    = __int_as_float((121 - k) << 23);      // 2^-(k+6)
        const float gain = fast_exp2(fmaf(em, LOG2E, cm2));      // emit + colmax fold-in
        const float s    = gain * r;

        // ---- MFMA block: 4 tiles x 2 K-chunks, depth-2 accumulate chains ----
        f4v z = {0.f, 0.f, 0.f, 0.f};
        f4v d0 = z, d1 = z, d2 = z, d3 = z;
        d0 = __builtin_amdgcn_mfma_scale_f32_16x16x128_f8f6f4(ua0, Efr[0][0], d0, 1, 0, 0, SC1, 0, SC1);
        d1 = __builtin_amdgcn_mfma_scale_f32_16x16x128_f8f6f4(ua0, Efr[1][0], d1, 1, 0, 0, SC1, 0, SC1);
        d2 = __builtin_amdgcn_mfma_scale_f32_16x16x128_f8f6f4(ua0, Efr[2][0], d2, 1, 0, 0, SC1, 0, SC1);
        d3 = __builtin_amdgcn_mfma_scale_f32_16x16x128_f8f6f4(ua0, Efr[3][0], d3, 1, 0, 0, SC1, 0, SC1);
        d0 = __builtin_amdgcn_mfma_scale_f32_16x16x128_f8f6f4(ua1, Efr[0][1], d0, 1, 0, 0, SC1, 0, SC1);
        d1 = __builtin_amdgcn_mfma_scale_f32_16x16x128_f8f6f4(ua1, Efr[1][1], d1, 1, 0, 0, SC1, 0, SC1);
        d2 = __builtin_amdgcn_mfma_scale_f32_16x16x128_f8f6f4(ua1, Efr[2][1], d2, 1, 0, 0, SC1, 0, SC1);
        d3 = __builtin_amdgcn_mfma_scale_f32_16x16x128_f8f6f4(ua1, Efr[3][1], d3, 1, 0, 0, SC1, 0, SC1);

        // rows replicated; thread j's column sits in tile lg, element 0. Static select.
        float vraw = (lg == 0) ? d0[0] : (lg == 1) ? d1[0] : (lg == 2) ? d2[0] : d3[0];

        if (t < T - 1) {
            C += (float)(k + 6);
            u_lds[t & 1][j] = f2bf8(vraw * s);   // short tail: mul, cvt, byte write
        } else {
            v = vraw * gain;                     // final step keeps unrenormed v
        }
        SYNC_LDS();
    }

    // ---- Z_b = ln2 * (C + log2(sum_j v_j)), v in scale 2^-C ----
    red[j] = v;
    __syncthreads();
    #pragma unroll
    for (int s2 = 128; s2 > 0; s2 >>= 1) {
        if (j < s2) red[j] += red[j + s2];
        __syncthreads();
    }
    float Z = (C + log2f(red[0])) * LN2;
    __syncthreads();   // everyone done reading red[0] before reuse

    // ---- gold score (gather) ----
    float gp = 0.f;
    const int*   tg  = tags + (size_t)b * T;
    const float* mk  = mask + (size_t)b * T;
    const float* emb = emissions + ((size_t)b * T) * N;
    for (int t = 1 + j; t < T; t += 256) {
        int tt = tg[t], tp = tg[t - 1];
        gp += (emb[(size_t)t * N + tt] + trans[(size_t)tp * N + tt]) * mk[t];
    }
    if (j == 0) gp += emb[tg[0]];
    red[j] = gp;
    __syncthreads();
    #pragma unroll
    for (int s2 = 128; s2 > 0; s2 >>= 1) {
        if (j < s2) red[j] += red[j + s2];
        __syncthreads();
    }
    if (j == 0) ws[b] = Z - red[0];
}

// Deterministic mean over the 128 per-batch results.
__global__ void crf_finalize(const float* __restrict__ ws, float* __restrict__ out) {
    int l = threadIdx.x;                 // 64 threads, one wave
    float s = ws[l] + ws[l + 64];
    #pragma unroll
    for (int d = 32; d > 0; d >>= 1) s += __shfl_down(s, d);
    if (l == 0) out[0] = s * (1.0f / 128.0f);
}

extern "C" void kernel_launch(void* const* d_in, const int* in_sizes, int n_in,
                              void* d_out, int out_size, void* d_ws, size_t ws_size,
                              hipStream_t stream) {
    const float* emissions = (const float*)d_in[0];
    const int*   tags      = (const int*)  d_in[1];
    const float* mask      = (const float*)d_in[2];
    const float* trans     = (const float*)d_in[3];
    float* out = (float*)d_out;
    float* ws  = (float*)d_ws;           // 128 floats of scratch

    crf_main<<<dim3(128), dim3(256), 0, stream>>>(emissions, tags, mask, trans, ws);
    crf_finalize<<<dim3(1), dim3(64), 0, stream>>>(ws, out);
}